// Round 12
// baseline (289.934 us; speedup 1.0000x reference)
//
#include <hip/hip_runtime.h>
#include <hip/hip_fp16.h>
#include <math.h>

#define FDIM   64
#define NB     64      // nodes per pre_gemm block
#define BSHIFT 7       // bucket = 128 nodes (block-exclusive in fusedB)
#define BMASK  127
#define CHUNKA 4096    // edges per block in scatter (measured-best amortization)
#define CHUNKM 2048    // edges per block in mm_k
#define CAP    3072    // LDS edge capacity per fusedB chunk
#define CAPB   3584    // fixed payload capacity per bucket (mean 2560, +20 sigma)

// ---------- mm_k: minmax partials only ----------
__global__ __launch_bounds__(256) void mm_k(const float* __restrict__ amount,
                                            const float* __restrict__ count,
                                            float4* __restrict__ partial, int E) {
  __shared__ float4 lred[4];
  float amin = 3.4e38f, amax = -3.4e38f, cmin = 3.4e38f, cmax = -3.4e38f;
  int e0 = blockIdx.x * CHUNKM + threadIdx.x * 8;
  if (e0 + 8 <= E) {
    #pragma unroll
    for (int q = 0; q < 8; q += 4) {
      float4 a4 = *(const float4*)(amount + e0 + q);
      float4 c4 = *(const float4*)(count + e0 + q);
      amin = fminf(amin, fminf(fminf(a4.x, a4.y), fminf(a4.z, a4.w)));
      amax = fmaxf(amax, fmaxf(fmaxf(a4.x, a4.y), fmaxf(a4.z, a4.w)));
      cmin = fminf(cmin, fminf(fminf(c4.x, c4.y), fminf(c4.z, c4.w)));
      cmax = fmaxf(cmax, fmaxf(fmaxf(c4.x, c4.y), fmaxf(c4.z, c4.w)));
    }
  } else {
    for (int e = e0; e < E; e++) {
      float a = amount[e], c = count[e];
      amin = fminf(amin, a); amax = fmaxf(amax, a);
      cmin = fminf(cmin, c); cmax = fmaxf(cmax, c);
    }
  }
  #pragma unroll
  for (int off = 32; off; off >>= 1) {
    amin = fminf(amin, __shfl_down(amin, off));
    amax = fmaxf(amax, __shfl_down(amax, off));
    cmin = fminf(cmin, __shfl_down(cmin, off));
    cmax = fmaxf(cmax, __shfl_down(cmax, off));
  }
  if ((threadIdx.x & 63) == 0) lred[threadIdx.x >> 6] = make_float4(amin, amax, cmin, cmax);
  __syncthreads();
  if (threadIdx.x == 0) {
    float4 r = lred[0];
    #pragma unroll
    for (int w = 1; w < 4; w++) {
      r.x = fminf(r.x, lred[w].x); r.y = fmaxf(r.y, lred[w].y);
      r.z = fminf(r.z, lred[w].z); r.w = fmaxf(r.w, lred[w].w);
    }
    partial[blockIdx.x] = r;
  }
}

// ---------- init_k: minmax final reduce + cursor init + colsum zero ----------
__global__ __launch_bounds__(256) void init_k(const float4* __restrict__ partial,
                                              int nb, float* __restrict__ mmf,
                                              int* __restrict__ cursor, int nbkt,
                                              double* __restrict__ colsum) {
  int t = threadIdx.x;
  for (int k = t; k < nbkt; k += 256) cursor[k] = k * CAPB;
  for (int i = t; i < 1024; i += 256) colsum[i] = 0.0;
  float amin = 3.4e38f, amax = -3.4e38f, cmin = 3.4e38f, cmax = -3.4e38f;
  for (int i = t; i < nb; i += 256) {
    float4 p = partial[i];
    amin = fminf(amin, p.x); amax = fmaxf(amax, p.y);
    cmin = fminf(cmin, p.z); cmax = fmaxf(cmax, p.w);
  }
  #pragma unroll
  for (int off = 32; off; off >>= 1) {
    amin = fminf(amin, __shfl_down(amin, off));
    amax = fmaxf(amax, __shfl_down(amax, off));
    cmin = fminf(cmin, __shfl_down(cmin, off));
    cmax = fmaxf(cmax, __shfl_down(cmax, off));
  }
  __shared__ float4 lred[4];
  if ((t & 63) == 0) lred[t >> 6] = make_float4(amin, amax, cmin, cmax);
  __syncthreads();
  if (t == 0) {
    float4 r = lred[0];
    #pragma unroll
    for (int w = 1; w < 4; w++) {
      r.x = fminf(r.x, lred[w].x); r.y = fmaxf(r.y, lred[w].y);
      r.z = fminf(r.z, lred[w].z); r.w = fmaxf(r.w, lred[w].w);
    }
    mmf[0] = r.x; mmf[1] = r.y; mmf[2] = r.z; mmf[3] = r.w;
  }
}

// ---------- sp_k: block-partitioned scatter (bid < nblkA) + pre_gemm ----------
// Scatter and pre_gemm are data-independent; merging them into one launch
// lets the latency-bound scatter waves overlap the FMA-bound pre_gemm waves
// (single-stream graph capture forbids multi-stream concurrency). LDS is a
// union: pre_gemm's 16 KB hs aliases scatter's lpay.
union SPMem {
  struct {
    int cntb[1024];
    int baseb[1024];
    int sbase[1024];
    int wsum[4];
    int2 lpay[CHUNKA];
    unsigned short lbkt[CHUNKA];
  } sc;
  float hs[NB * FDIM];   // 16 KB
};

__global__ __launch_bounds__(256) void sp_k(const int* __restrict__ src,
                                            const int* __restrict__ dst,
                                            const float* __restrict__ amount,
                                            const float* __restrict__ count,
                                            const float* __restrict__ mmf,
                                            int* __restrict__ cursor,
                                            int2* __restrict__ payload,
                                            const float* __restrict__ h,
                                            const float* __restrict__ fc_w,
                                            const float* __restrict__ fc_b,
                                            float* __restrict__ G1,
                                            __half2* __restrict__ P,
                                            int E, int nbkt, int nblkA, int N) {
  __shared__ SPMem sm;
  const int t = threadIdx.x;
  if (blockIdx.x < nblkA) {
    // ================= scatter body =================
    const int blk = blockIdx.x;
    for (int k = t; k < nbkt; k += 256) sm.sc.cntb[k] = 0;
    __syncthreads();
    const float amin = mmf[0], amax = mmf[1], cmin = mmf[2], cmax = mmf[3];
    const float L2E = 1.4426950408889634f;
    const float ascale = 0.5f * L2E / (amax - amin + 1e-8f);
    const float cscale = 0.5f * L2E / (cmax - cmin + 1e-8f);
    int e0 = blk * CHUNKA + t * 16;
    const bool full = (e0 + 16 <= E);
    int4 S[4]; int4 D[4]; float4 A[4]; float4 C[4];
    if (full) {
      #pragma unroll
      for (int q = 0; q < 4; q++) {
        S[q] = *(const int4*)(src + e0 + 4 * q);
        D[q] = *(const int4*)(dst + e0 + 4 * q);
        A[q] = *(const float4*)(amount + e0 + 4 * q);
        C[q] = *(const float4*)(count + e0 + 4 * q);
        atomicAdd(&sm.sc.cntb[S[q].x >> BSHIFT], 1);
        atomicAdd(&sm.sc.cntb[S[q].y >> BSHIFT], 1);
        atomicAdd(&sm.sc.cntb[S[q].z >> BSHIFT], 1);
        atomicAdd(&sm.sc.cntb[S[q].w >> BSHIFT], 1);
      }
    } else {
      for (int e = e0; e < E; e++) atomicAdd(&sm.sc.cntb[src[e] >> BSHIFT], 1);
    }
    __syncthreads();
    // exclusive scan of cntb[0..nbkt) -> baseb : wave-shuffle scan
    {
      const int wv = t >> 6, ln = t & 63;
      int carry = 0;
      #pragma unroll
      for (int c = 0; c < 4; c++) {
        int idx = (wv << 8) + (c << 6) + ln;
        int x = (idx < nbkt) ? sm.sc.cntb[idx] : 0;
        int v = x;
        #pragma unroll
        for (int off = 1; off < 64; off <<= 1) {
          int u = __shfl_up(v, off);
          if (ln >= off) v += u;
        }
        if (idx < nbkt) sm.sc.baseb[idx] = carry + v - x;
        carry += __shfl(v, 63);
      }
      if (ln == 0) sm.sc.wsum[wv] = carry;
    }
    __syncthreads();
    {
      const int wv = t >> 6, ln = t & 63;
      int wpre = 0;
      #pragma unroll
      for (int i = 0; i < 4; i++) wpre += (i < wv) ? sm.sc.wsum[i] : 0;
      if (wpre) {
        #pragma unroll
        for (int c = 0; c < 4; c++) {
          int idx = (wv << 8) + (c << 6) + ln;
          if (idx < nbkt) sm.sc.baseb[idx] += wpre;
        }
      }
    }
    __syncthreads();
    // reserve global space per nonzero bucket; reset cntb to local cursor
    for (int k = t; k < nbkt; k += 256) {
      int cnt = sm.sc.cntb[k];
      if (cnt) sm.sc.sbase[k] = atomicAdd(&cursor[k], cnt);
      sm.sc.cntb[k] = sm.sc.baseb[k];
    }
    __syncthreads();
    auto ins = [&](int s, int d, float a, float c) {
      int b = s >> BSHIFT;
      float ew = (a - amin) * ascale + (c - cmin) * cscale;
      int pos = atomicAdd(&sm.sc.cntb[b], 1);
      sm.sc.lpay[pos] = make_int2((d << 8) | (s & BMASK), __float_as_int(ew));
      sm.sc.lbkt[pos] = (unsigned short)b;
    };
    if (full) {
      #pragma unroll
      for (int q = 0; q < 4; q++) {
        ins(S[q].x, D[q].x, A[q].x, C[q].x);
        ins(S[q].y, D[q].y, A[q].y, C[q].y);
        ins(S[q].z, D[q].z, A[q].z, C[q].z);
        ins(S[q].w, D[q].w, A[q].w, C[q].w);
      }
    } else {
      for (int e = e0; e < E; e++) ins(src[e], dst[e], amount[e], count[e]);
    }
    __syncthreads();
    const int ned = min(CHUNKA, E - blk * CHUNKA);
    for (int i = t; i < ned; i += 256) {
      int bk = sm.sc.lbkt[i];
      int gpos = sm.sc.sbase[bk] + (i - sm.sc.baseb[bk]);
      if (gpos < (bk + 1) * CAPB)          // overflow guard (statistically unreachable)
        payload[gpos] = sm.sc.lpay[i];
    }
  } else {
    // ================= pre_gemm body (256 threads: 4 groups of 64) =========
    // groups: (half = grp&1) selects G1 vs P output; (grp>>1) selects row half.
    const int pgb = blockIdx.x - nblkA;
    const int o = t & 63;
    const int grp = t >> 6;
    const int half = grp & 1;
    const int rh = grp >> 1;
    float w[FDIM];
    const float* wrow = fc_w + o * 128 + half * 64;
    #pragma unroll
    for (int f = 0; f < FDIM; f += 4) {
      float4 v = *(const float4*)(wrow + f);
      w[f] = v.x; w[f + 1] = v.y; w[f + 2] = v.z; w[f + 3] = v.w;
    }
    const float bias = (half == 0) ? fc_b[o] : 0.0f;
    const int n0 = pgb * NB;
    const int nrows = min(NB, N - n0);
    for (int i = t; i < nrows * FDIM; i += 256) sm.hs[i] = h[(size_t)n0 * FDIM + i];
    __syncthreads();
    const int r0 = rh * (NB / 2);
    const int r1 = min(r0 + NB / 2, nrows);
    for (int n = r0; n < r1; n++) {
      float4 a4 = make_float4(0.f, 0.f, 0.f, 0.f);
      #pragma unroll
      for (int f = 0; f < FDIM; f += 4) {
        float4 hv = *(const float4*)(&sm.hs[n * FDIM + f]);
        a4.x += hv.x * w[f];
        a4.y += hv.y * w[f + 1];
        a4.z += hv.z * w[f + 2];
        a4.w += hv.w * w[f + 3];
      }
      float acc = (a4.x + a4.y) + (a4.z + a4.w) + bias;
      if (half == 0) {
        G1[(size_t)(n0 + n) * FDIM + o] = acc;
      } else {
        P[(size_t)(n0 + n) * FDIM + o] =
            __halves2half2(__float2half(acc), __float2half(sm.hs[n * FDIM + o]));
      }
    }
  }
}

__device__ __forceinline__ float2 unpack_h2(unsigned u) {
  __half2 v = *(__half2*)&u;
  return make_float2(__low2float(v), __high2float(v));
}

// ---------- fusedB: one 8-wave block per 128-node bucket; LDS fine-sort +
// register accumulate (proven 112-us structure). base = b*CAPB (fixed region),
// end = cursor[b] (final reservation). Exclusive ownership -> plain stores for
// wave-interior nodes, atomicAdd only at wave boundaries.
__global__ __launch_bounds__(512) void fusedB_k(const int2* __restrict__ payload,
                                                const int* __restrict__ cursor,
                                                const float* __restrict__ G1,
                                                const unsigned* __restrict__ P,
                                                double* __restrict__ colsum,
                                                float* __restrict__ out,
                                                int E, int nbkt) {
  __shared__ int2 lpay[CAP];        // 24 KB
  __shared__ int fcnt[128];
  __shared__ int fcur[128];
  __shared__ float part[512];
  const int b = blockIdx.x;
  const int t = threadIdx.x;
  const int lane = t & 63;
  const int wv = __builtin_amdgcn_readfirstlane(t >> 6);   // 0..7
  const int node0 = b << BSHIFT;
  const int base = b * CAPB;
  int end = cursor[b];
  if (end > base + CAPB) end = base + CAPB;
  const int nchunks = (end - base + CAP - 1) / CAP;        // ==1 in practice
  const bool multi = (nchunks > 1);                        // safety fallback
  float csum = 0.0f;
  for (int c = 0; c < nchunks; c++) {
    const int cs = base + c * CAP;
    const int m = min(CAP, end - cs);
    if (t < 128) fcnt[t] = 0;
    __syncthreads();
    // stage to regs (static-indexed) + fine histogram
    int2 myp0, myp1, myp2, myp3, myp4, myp5;
    {
      int i;
      i = t;        if (i < m) { myp0 = payload[cs + i]; atomicAdd(&fcnt[myp0.x & 127], 1); }
      i = t + 512;  if (i < m) { myp1 = payload[cs + i]; atomicAdd(&fcnt[myp1.x & 127], 1); }
      i = t + 1024; if (i < m) { myp2 = payload[cs + i]; atomicAdd(&fcnt[myp2.x & 127], 1); }
      i = t + 1536; if (i < m) { myp3 = payload[cs + i]; atomicAdd(&fcnt[myp3.x & 127], 1); }
      i = t + 2048; if (i < m) { myp4 = payload[cs + i]; atomicAdd(&fcnt[myp4.x & 127], 1); }
      i = t + 2560; if (i < m) { myp5 = payload[cs + i]; atomicAdd(&fcnt[myp5.x & 127], 1); }
    }
    __syncthreads();
    // wave 0: exclusive scan of fcnt[0..128) -> fcur
    if (wv == 0) {
      int carry = 0;
      #pragma unroll
      for (int cc = 0; cc < 2; cc++) {
        int idx = (cc << 6) + lane;
        int x = fcnt[idx];
        int v = x;
        #pragma unroll
        for (int off = 1; off < 64; off <<= 1) {
          int u = __shfl_up(v, off);
          if (lane >= off) v += u;
        }
        fcur[idx] = carry + v - x;
        carry += __shfl(v, 63);
      }
    }
    __syncthreads();
    // scatter regs -> lpay (fine-sorted)
    {
      int i;
      i = t;        if (i < m) lpay[atomicAdd(&fcur[myp0.x & 127], 1)] = myp0;
      i = t + 512;  if (i < m) lpay[atomicAdd(&fcur[myp1.x & 127], 1)] = myp1;
      i = t + 1024; if (i < m) lpay[atomicAdd(&fcur[myp2.x & 127], 1)] = myp2;
      i = t + 1536; if (i < m) lpay[atomicAdd(&fcur[myp3.x & 127], 1)] = myp3;
      i = t + 2048; if (i < m) lpay[atomicAdd(&fcur[myp4.x & 127], 1)] = myp4;
      i = t + 2560; if (i < m) lpay[atomicAdd(&fcur[myp5.x & 127], 1)] = myp5;
    }
    __syncthreads();
    // per-wave subranges over the sorted segment
    const int per = (((m + 7) >> 3) + 63) & ~63;
    const int ws = wv * per;
    const int we = min(ws + per, m);
    int curnode = -1;
    bool firstf = true;
    float acc = 0.0f, g1 = 0.0f;
    auto flush_to = [&](int node) {   // wave-uniform control
      if (curnode >= 0) {
        float* dp = out + (size_t)curnode * FDIM + lane;
        if (multi || firstf) { atomicAdd(dp, acc); firstf = false; }
        else *dp = acc;
      }
      curnode = node; acc = 0.0f;
      g1 = G1[(size_t)node * FDIM + lane];
    };
    for (int c0 = ws; c0 < we; c0 += 64) {
      const int mm = min(64, we - c0);
      int2 p = make_int2(0, 0);
      if (lane < mm) p = lpay[c0 + lane];
      if (mm == 64) {
        #pragma unroll 1
        for (int j = 0; j < 64; j += 16) {
          int xs[16]; float ee[16]; unsigned uu[16];
          #pragma unroll
          for (int k = 0; k < 16; k++) {
            xs[k] = __builtin_amdgcn_readlane(p.x, j + k);
            ee[k] = __int_as_float(__builtin_amdgcn_readlane(p.y, j + k));
          }
          #pragma unroll
          for (int k = 0; k < 16; k++) {
            unsigned off = (((unsigned)xs[k]) & 0xFFFFFF00u) | ((unsigned)lane << 2);
            uu[k] = *(const unsigned*)((const char*)P + off);
          }
          #pragma unroll
          for (int k = 0; k < 16; k++) {
            int node = node0 + (xs[k] & 127);
            if (node != curnode) flush_to(node);
            float2 v = unpack_h2(uu[k]);
            float sc = g1 + v.x;
            sc = fmaxf(sc, 0.01f * sc);        // leaky_relu
            float x = exp2f(sc * ee[k]);       // log2e folded into ew
            csum += x;
            acc += x * v.y;
          }
        }
      } else {
        for (int j = 0; j < mm; j += 16) {
          const int rem = mm - j;
          int xs[16]; float ee[16]; unsigned uu[16];
          #pragma unroll
          for (int k = 0; k < 16; k++) {
            xs[k] = __builtin_amdgcn_readlane(p.x, j + k);
            ee[k] = __int_as_float(__builtin_amdgcn_readlane(p.y, j + k));
          }
          #pragma unroll
          for (int k = 0; k < 16; k++) {
            unsigned off = (((unsigned)xs[k]) & 0xFFFFFF00u) | ((unsigned)lane << 2);
            uu[k] = *(const unsigned*)((const char*)P + off);
          }
          #pragma unroll
          for (int k = 0; k < 16; k++) {
            if (k < rem) {                      // wave-uniform guard
              int node = node0 + (xs[k] & 127);
              if (node != curnode) flush_to(node);
              float2 v = unpack_h2(uu[k]);
              float sc = g1 + v.x;
              sc = fmaxf(sc, 0.01f * sc);
              float x = exp2f(sc * ee[k]);
              csum += x;
              acc += x * v.y;
            }
          }
        }
      }
    }
    if (curnode >= 0) atomicAdd(out + (size_t)curnode * FDIM + lane, acc);  // range-end: always atomic
    __syncthreads();   // lpay reuse safety for multi-chunk
  }
  part[t] = csum;
  __syncthreads();
  if (t < 64) {
    float tot = 0.0f;
    #pragma unroll
    for (int w = 0; w < 8; w++) tot += part[t + (w << 6)];
    atomicAdd(&colsum[t * 16], (double)tot);   // 128B line per feature
  }
}

// ---------- epilogue: out *= 1/colsum[feature], float4 ----------
__global__ __launch_bounds__(256) void scale_k(float4* __restrict__ out4,
                                               const double* __restrict__ colsum,
                                               int total4) {
  __shared__ float rinv_s[64];
  if (threadIdx.x < 64) rinv_s[threadIdx.x] = (float)(1.0 / colsum[threadIdx.x * 16]);
  __syncthreads();
  const float4* r4 = (const float4*)rinv_s;
  int idx = blockIdx.x * blockDim.x + threadIdx.x;
  int stride = gridDim.x * blockDim.x;
  for (int i = idx; i < total4; i += stride) {
    float4 v = out4[i];
    float4 r = r4[i & 15];
    v.x *= r.x; v.y *= r.y; v.z *= r.z; v.w *= r.w;
    out4[i] = v;
  }
}

extern "C" void kernel_launch(void* const* d_in, const int* in_sizes, int n_in,
                              void* d_out, int out_size, void* d_ws, size_t ws_size,
                              hipStream_t stream) {
  const float* h      = (const float*)d_in[0];
  const int*   adj    = (const int*)d_in[1];
  const float* amount = (const float*)d_in[2];
  const float* count  = (const float*)d_in[3];
  const float* fc_w   = (const float*)d_in[4];
  const float* fc_b   = (const float*)d_in[5];
  float* out = (float*)d_out;

  const int E = in_sizes[2];
  const int N = in_sizes[0] / FDIM;
  const int* src = adj;
  const int* dst = adj + E;
  const int nbkt  = (N + BMASK) >> BSHIFT;           // 128-node buckets (<=1024)
  const int nblkA = (E + CHUNKA - 1) / CHUNKA;
  const int nblkM = (E + CHUNKM - 1) / CHUNKM;
  const int npg   = (N + NB - 1) / NB;

  // ---- workspace layout (256B-aligned) ----
  char* ws = (char*)d_ws;
  size_t off = 0;
  auto alloc = [&](size_t bytes) { void* p = ws + off; off += (bytes + 255) & ~(size_t)255; return p; };
  float*    G1      = (float*)alloc((size_t)N * FDIM * sizeof(float));
  __half2*  P       = (__half2*)alloc((size_t)N * FDIM * sizeof(__half2));
  int2*     payload = (int2*)alloc((size_t)nbkt * CAPB * sizeof(int2));
  int*      cursor  = (int*)alloc(1024 * sizeof(int));
  float4*   mmpart  = (float4*)alloc((size_t)nblkM * sizeof(float4));
  double*   colsum  = (double*)alloc(1024 * sizeof(double));   // padded: [f*16]
  float*    mmf     = (float*)alloc(4 * sizeof(float));

  mm_k<<<nblkM, 256, 0, stream>>>(amount, count, mmpart, E);
  init_k<<<1, 256, 0, stream>>>(mmpart, nblkM, mmf, cursor, nbkt, colsum);
  sp_k<<<nblkA + npg, 256, 0, stream>>>(src, dst, amount, count, mmf, cursor, payload,
                                        h, fc_w, fc_b, G1, P, E, nbkt, nblkA, N);
  fusedB_k<<<nbkt, 512, 0, stream>>>(payload, cursor, G1, (const unsigned*)P, colsum, out, E, nbkt);
  scale_k<<<1024, 256, 0, stream>>>((float4*)out, colsum, N * FDIM / 4);
}

// Round 13
// 279.843 us; speedup vs baseline: 1.0361x; 1.0361x over previous
//
#include <hip/hip_runtime.h>
#include <hip/hip_fp16.h>
#include <math.h>

#define FDIM   64
#define NB     64      // nodes per pre_gemm block
#define BSHIFT 7       // bucket = 128 nodes (block-exclusive in fusedB)
#define BMASK  127
#define CHUNKA 4096    // edges per block in scatter (measured-best amortization)
#define CHUNKM 2048    // edges per block in mm sweep
#define CAP    3072    // LDS edge capacity per fusedB chunk
#define CAPB   3584    // fixed payload capacity per bucket (mean 2560, +20 sigma)

// ---------- mp_k: partitioned {minmax sweep | pre_gemm} ----------
// Both phases are data-independent; merging hides the 16 MB minmax stream
// under pre_gemm's FMA phase. Branch LDS footprints match (<=16 KB), unlike
// round-12's failed scatter merge (53 KB union killed pre_gemm occupancy).
// pre_gemm: 256 threads = 4 groups of 64; group = (half = G1|P) x (row half).
__global__ __launch_bounds__(256) void mp_k(const float* __restrict__ amount,
                                            const float* __restrict__ count,
                                            float4* __restrict__ partial,
                                            const float* __restrict__ h,
                                            const float* __restrict__ fc_w,
                                            const float* __restrict__ fc_b,
                                            float* __restrict__ G1,
                                            __half2* __restrict__ P,
                                            int E, int N, int nblkM) {
  __shared__ float hs[NB * FDIM];   // 16 KB (mm branch uses first 64 B)
  const int t = threadIdx.x;
  if (blockIdx.x < nblkM) {
    // ================= minmax sweep =================
    float amin = 3.4e38f, amax = -3.4e38f, cmin = 3.4e38f, cmax = -3.4e38f;
    int e0 = blockIdx.x * CHUNKM + t * 8;
    if (e0 + 8 <= E) {
      #pragma unroll
      for (int q = 0; q < 8; q += 4) {
        float4 a4 = *(const float4*)(amount + e0 + q);
        float4 c4 = *(const float4*)(count + e0 + q);
        amin = fminf(amin, fminf(fminf(a4.x, a4.y), fminf(a4.z, a4.w)));
        amax = fmaxf(amax, fmaxf(fmaxf(a4.x, a4.y), fmaxf(a4.z, a4.w)));
        cmin = fminf(cmin, fminf(fminf(c4.x, c4.y), fminf(c4.z, c4.w)));
        cmax = fmaxf(cmax, fmaxf(fmaxf(c4.x, c4.y), fmaxf(c4.z, c4.w)));
      }
    } else {
      for (int e = e0; e < E; e++) {
        float a = amount[e], c = count[e];
        amin = fminf(amin, a); amax = fmaxf(amax, a);
        cmin = fminf(cmin, c); cmax = fmaxf(cmax, c);
      }
    }
    #pragma unroll
    for (int off = 32; off; off >>= 1) {
      amin = fminf(amin, __shfl_down(amin, off));
      amax = fmaxf(amax, __shfl_down(amax, off));
      cmin = fminf(cmin, __shfl_down(cmin, off));
      cmax = fmaxf(cmax, __shfl_down(cmax, off));
    }
    float4* lred = (float4*)hs;
    if ((t & 63) == 0) lred[t >> 6] = make_float4(amin, amax, cmin, cmax);
    __syncthreads();
    if (t == 0) {
      float4 r = lred[0];
      #pragma unroll
      for (int w = 1; w < 4; w++) {
        r.x = fminf(r.x, lred[w].x); r.y = fmaxf(r.y, lred[w].y);
        r.z = fminf(r.z, lred[w].z); r.w = fmaxf(r.w, lred[w].w);
      }
      partial[blockIdx.x] = r;
    }
  } else {
    // ================= pre_gemm (4 groups of 64) =================
    const int pgb = blockIdx.x - nblkM;
    const int o = t & 63;
    const int grp = t >> 6;
    const int half = grp & 1;
    const int rh = grp >> 1;
    float w[FDIM];
    const float* wrow = fc_w + o * 128 + half * 64;
    #pragma unroll
    for (int f = 0; f < FDIM; f += 4) {
      float4 v = *(const float4*)(wrow + f);
      w[f] = v.x; w[f + 1] = v.y; w[f + 2] = v.z; w[f + 3] = v.w;
    }
    const float bias = (half == 0) ? fc_b[o] : 0.0f;
    const int n0 = pgb * NB;
    const int nrows = min(NB, N - n0);
    for (int i = t; i < nrows * FDIM; i += 256) hs[i] = h[(size_t)n0 * FDIM + i];
    __syncthreads();
    const int r0 = rh * (NB / 2);
    const int r1 = min(r0 + NB / 2, nrows);
    for (int n = r0; n < r1; n++) {
      float4 a4 = make_float4(0.f, 0.f, 0.f, 0.f);
      #pragma unroll
      for (int f = 0; f < FDIM; f += 4) {
        float4 hv = *(const float4*)(&hs[n * FDIM + f]);
        a4.x += hv.x * w[f];
        a4.y += hv.y * w[f + 1];
        a4.z += hv.z * w[f + 2];
        a4.w += hv.w * w[f + 3];
      }
      float acc = (a4.x + a4.y) + (a4.z + a4.w) + bias;
      if (half == 0) {
        G1[(size_t)(n0 + n) * FDIM + o] = acc;
      } else {
        P[(size_t)(n0 + n) * FDIM + o] =
            __halves2half2(__float2half(acc), __float2half(hs[n * FDIM + o]));
      }
    }
  }
}

// ---------- init_k: minmax final reduce + cursor init + colsum zero ----------
__global__ __launch_bounds__(256) void init_k(const float4* __restrict__ partial,
                                              int nb, float* __restrict__ mmf,
                                              int* __restrict__ cursor, int nbkt,
                                              double* __restrict__ colsum) {
  int t = threadIdx.x;
  for (int k = t; k < nbkt; k += 256) cursor[k] = k * CAPB;
  for (int i = t; i < 1024; i += 256) colsum[i] = 0.0;
  float amin = 3.4e38f, amax = -3.4e38f, cmin = 3.4e38f, cmax = -3.4e38f;
  for (int i = t; i < nb; i += 256) {
    float4 p = partial[i];
    amin = fminf(amin, p.x); amax = fmaxf(amax, p.y);
    cmin = fminf(cmin, p.z); cmax = fmaxf(cmax, p.w);
  }
  #pragma unroll
  for (int off = 32; off; off >>= 1) {
    amin = fminf(amin, __shfl_down(amin, off));
    amax = fmaxf(amax, __shfl_down(amax, off));
    cmin = fminf(cmin, __shfl_down(cmin, off));
    cmax = fmaxf(cmax, __shfl_down(cmax, off));
  }
  __shared__ float4 lred[4];
  if ((t & 63) == 0) lred[t >> 6] = make_float4(amin, amax, cmin, cmax);
  __syncthreads();
  if (t == 0) {
    float4 r = lred[0];
    #pragma unroll
    for (int w = 1; w < 4; w++) {
      r.x = fminf(r.x, lred[w].x); r.y = fmaxf(r.y, lred[w].y);
      r.z = fminf(r.z, lred[w].z); r.w = fmaxf(r.w, lred[w].w);
    }
    mmf[0] = r.x; mmf[1] = r.y; mmf[2] = r.z; mmf[3] = r.w;
  }
}

// ---------- scatter: LDS counting sort -> fixed-capacity bucket regions ----------
// cursor[k] starts at k*CAPB; per-(block,bucket) space reserved with one global
// atomicAdd. payload.x = (dst << 8) | fine, payload.y = (ew * log2e) bits
__global__ __launch_bounds__(256) void scatter_k(const int* __restrict__ src,
                                                 const int* __restrict__ dst,
                                                 const float* __restrict__ amount,
                                                 const float* __restrict__ count,
                                                 const float* __restrict__ mmf,
                                                 int* __restrict__ cursor,
                                                 int2* __restrict__ payload,
                                                 int E, int nbkt) {
  __shared__ int cntb[1024];
  __shared__ int baseb[1024];
  __shared__ int sbase[1024];
  __shared__ int wsum[4];
  __shared__ int2 lpay[CHUNKA];
  __shared__ unsigned short lbkt[CHUNKA];
  const int t = threadIdx.x, blk = blockIdx.x;
  for (int k = t; k < nbkt; k += 256) cntb[k] = 0;
  __syncthreads();
  const float amin = mmf[0], amax = mmf[1], cmin = mmf[2], cmax = mmf[3];
  const float L2E = 1.4426950408889634f;
  const float ascale = 0.5f * L2E / (amax - amin + 1e-8f);
  const float cscale = 0.5f * L2E / (cmax - cmin + 1e-8f);
  int e0 = blk * CHUNKA + t * 16;
  const bool full = (e0 + 16 <= E);
  int4 S[4]; int4 D[4]; float4 A[4]; float4 C[4];
  if (full) {
    #pragma unroll
    for (int q = 0; q < 4; q++) {
      S[q] = *(const int4*)(src + e0 + 4 * q);
      D[q] = *(const int4*)(dst + e0 + 4 * q);
      A[q] = *(const float4*)(amount + e0 + 4 * q);
      C[q] = *(const float4*)(count + e0 + 4 * q);
      atomicAdd(&cntb[S[q].x >> BSHIFT], 1);
      atomicAdd(&cntb[S[q].y >> BSHIFT], 1);
      atomicAdd(&cntb[S[q].z >> BSHIFT], 1);
      atomicAdd(&cntb[S[q].w >> BSHIFT], 1);
    }
  } else {
    for (int e = e0; e < E; e++) atomicAdd(&cntb[src[e] >> BSHIFT], 1);
  }
  __syncthreads();
  // exclusive scan of cntb[0..nbkt) -> baseb : wave-shuffle scan
  {
    const int wv = t >> 6, ln = t & 63;
    int carry = 0;
    #pragma unroll
    for (int c = 0; c < 4; c++) {
      int idx = (wv << 8) + (c << 6) + ln;
      int x = (idx < nbkt) ? cntb[idx] : 0;
      int v = x;
      #pragma unroll
      for (int off = 1; off < 64; off <<= 1) {
        int u = __shfl_up(v, off);
        if (ln >= off) v += u;
      }
      if (idx < nbkt) baseb[idx] = carry + v - x;
      carry += __shfl(v, 63);
    }
    if (ln == 0) wsum[wv] = carry;
  }
  __syncthreads();
  {
    const int wv = t >> 6, ln = t & 63;
    int wpre = 0;
    #pragma unroll
    for (int i = 0; i < 4; i++) wpre += (i < wv) ? wsum[i] : 0;
    if (wpre) {
      #pragma unroll
      for (int c = 0; c < 4; c++) {
        int idx = (wv << 8) + (c << 6) + ln;
        if (idx < nbkt) baseb[idx] += wpre;
      }
    }
  }
  __syncthreads();
  // reserve global space per nonzero bucket; reset cntb to local cursor
  for (int k = t; k < nbkt; k += 256) {
    int cnt = cntb[k];
    if (cnt) sbase[k] = atomicAdd(&cursor[k], cnt);
    cntb[k] = baseb[k];
  }
  __syncthreads();
  auto ins = [&](int s, int d, float a, float c) {
    int b = s >> BSHIFT;
    float ew = (a - amin) * ascale + (c - cmin) * cscale;
    int pos = atomicAdd(&cntb[b], 1);
    lpay[pos] = make_int2((d << 8) | (s & BMASK), __float_as_int(ew));
    lbkt[pos] = (unsigned short)b;
  };
  if (full) {
    #pragma unroll
    for (int q = 0; q < 4; q++) {
      ins(S[q].x, D[q].x, A[q].x, C[q].x);
      ins(S[q].y, D[q].y, A[q].y, C[q].y);
      ins(S[q].z, D[q].z, A[q].z, C[q].z);
      ins(S[q].w, D[q].w, A[q].w, C[q].w);
    }
  } else {
    for (int e = e0; e < E; e++) ins(src[e], dst[e], amount[e], count[e]);
  }
  __syncthreads();
  const int ned = min(CHUNKA, E - blk * CHUNKA);
  for (int i = t; i < ned; i += 256) {
    int bk = lbkt[i];
    int gpos = sbase[bk] + (i - baseb[bk]);
    if (gpos < (bk + 1) * CAPB)          // overflow guard (statistically unreachable)
      payload[gpos] = lpay[i];
  }
}

__device__ __forceinline__ float2 unpack_h2(unsigned u) {
  __half2 v = *(__half2*)&u;
  return make_float2(__low2float(v), __high2float(v));
}

// ---------- fusedB: one 8-wave block per 128-node bucket; LDS fine-sort +
// register accumulate (proven 112-us structure). base = b*CAPB (fixed region),
// end = cursor[b] (final reservation). Exclusive ownership -> plain stores for
// wave-interior nodes, atomicAdd only at wave boundaries.
__global__ __launch_bounds__(512) void fusedB_k(const int2* __restrict__ payload,
                                                const int* __restrict__ cursor,
                                                const float* __restrict__ G1,
                                                const unsigned* __restrict__ P,
                                                double* __restrict__ colsum,
                                                float* __restrict__ out,
                                                int E, int nbkt) {
  __shared__ int2 lpay[CAP];        // 24 KB
  __shared__ int fcnt[128];
  __shared__ int fcur[128];
  __shared__ float part[512];
  const int b = blockIdx.x;
  const int t = threadIdx.x;
  const int lane = t & 63;
  const int wv = __builtin_amdgcn_readfirstlane(t >> 6);   // 0..7
  const int node0 = b << BSHIFT;
  const int base = b * CAPB;
  int end = cursor[b];
  if (end > base + CAPB) end = base + CAPB;
  const int nchunks = (end - base + CAP - 1) / CAP;        // ==1 in practice
  const bool multi = (nchunks > 1);                        // safety fallback
  float csum = 0.0f;
  for (int c = 0; c < nchunks; c++) {
    const int cs = base + c * CAP;
    const int m = min(CAP, end - cs);
    if (t < 128) fcnt[t] = 0;
    __syncthreads();
    // stage to regs (static-indexed) + fine histogram
    int2 myp0, myp1, myp2, myp3, myp4, myp5;
    {
      int i;
      i = t;        if (i < m) { myp0 = payload[cs + i]; atomicAdd(&fcnt[myp0.x & 127], 1); }
      i = t + 512;  if (i < m) { myp1 = payload[cs + i]; atomicAdd(&fcnt[myp1.x & 127], 1); }
      i = t + 1024; if (i < m) { myp2 = payload[cs + i]; atomicAdd(&fcnt[myp2.x & 127], 1); }
      i = t + 1536; if (i < m) { myp3 = payload[cs + i]; atomicAdd(&fcnt[myp3.x & 127], 1); }
      i = t + 2048; if (i < m) { myp4 = payload[cs + i]; atomicAdd(&fcnt[myp4.x & 127], 1); }
      i = t + 2560; if (i < m) { myp5 = payload[cs + i]; atomicAdd(&fcnt[myp5.x & 127], 1); }
    }
    __syncthreads();
    // wave 0: exclusive scan of fcnt[0..128) -> fcur
    if (wv == 0) {
      int carry = 0;
      #pragma unroll
      for (int cc = 0; cc < 2; cc++) {
        int idx = (cc << 6) + lane;
        int x = fcnt[idx];
        int v = x;
        #pragma unroll
        for (int off = 1; off < 64; off <<= 1) {
          int u = __shfl_up(v, off);
          if (lane >= off) v += u;
        }
        fcur[idx] = carry + v - x;
        carry += __shfl(v, 63);
      }
    }
    __syncthreads();
    // scatter regs -> lpay (fine-sorted)
    {
      int i;
      i = t;        if (i < m) lpay[atomicAdd(&fcur[myp0.x & 127], 1)] = myp0;
      i = t + 512;  if (i < m) lpay[atomicAdd(&fcur[myp1.x & 127], 1)] = myp1;
      i = t + 1024; if (i < m) lpay[atomicAdd(&fcur[myp2.x & 127], 1)] = myp2;
      i = t + 1536; if (i < m) lpay[atomicAdd(&fcur[myp3.x & 127], 1)] = myp3;
      i = t + 2048; if (i < m) lpay[atomicAdd(&fcur[myp4.x & 127], 1)] = myp4;
      i = t + 2560; if (i < m) lpay[atomicAdd(&fcur[myp5.x & 127], 1)] = myp5;
    }
    __syncthreads();
    // per-wave subranges over the sorted segment
    const int per = (((m + 7) >> 3) + 63) & ~63;
    const int ws = wv * per;
    const int we = min(ws + per, m);
    int curnode = -1;
    bool firstf = true;
    float acc = 0.0f, g1 = 0.0f;
    auto flush_to = [&](int node) {   // wave-uniform control
      if (curnode >= 0) {
        float* dp = out + (size_t)curnode * FDIM + lane;
        if (multi || firstf) { atomicAdd(dp, acc); firstf = false; }
        else *dp = acc;
      }
      curnode = node; acc = 0.0f;
      g1 = G1[(size_t)node * FDIM + lane];
    };
    for (int c0 = ws; c0 < we; c0 += 64) {
      const int mm = min(64, we - c0);
      int2 p = make_int2(0, 0);
      if (lane < mm) p = lpay[c0 + lane];
      if (mm == 64) {
        #pragma unroll 1
        for (int j = 0; j < 64; j += 16) {
          int xs[16]; float ee[16]; unsigned uu[16];
          #pragma unroll
          for (int k = 0; k < 16; k++) {
            xs[k] = __builtin_amdgcn_readlane(p.x, j + k);
            ee[k] = __int_as_float(__builtin_amdgcn_readlane(p.y, j + k));
          }
          #pragma unroll
          for (int k = 0; k < 16; k++) {
            unsigned off = (((unsigned)xs[k]) & 0xFFFFFF00u) | ((unsigned)lane << 2);
            uu[k] = *(const unsigned*)((const char*)P + off);
          }
          #pragma unroll
          for (int k = 0; k < 16; k++) {
            int node = node0 + (xs[k] & 127);
            if (node != curnode) flush_to(node);
            float2 v = unpack_h2(uu[k]);
            float sc = g1 + v.x;
            sc = fmaxf(sc, 0.01f * sc);        // leaky_relu
            float x = exp2f(sc * ee[k]);       // log2e folded into ew
            csum += x;
            acc += x * v.y;
          }
        }
      } else {
        for (int j = 0; j < mm; j += 16) {
          const int rem = mm - j;
          int xs[16]; float ee[16]; unsigned uu[16];
          #pragma unroll
          for (int k = 0; k < 16; k++) {
            xs[k] = __builtin_amdgcn_readlane(p.x, j + k);
            ee[k] = __int_as_float(__builtin_amdgcn_readlane(p.y, j + k));
          }
          #pragma unroll
          for (int k = 0; k < 16; k++) {
            unsigned off = (((unsigned)xs[k]) & 0xFFFFFF00u) | ((unsigned)lane << 2);
            uu[k] = *(const unsigned*)((const char*)P + off);
          }
          #pragma unroll
          for (int k = 0; k < 16; k++) {
            if (k < rem) {                      // wave-uniform guard
              int node = node0 + (xs[k] & 127);
              if (node != curnode) flush_to(node);
              float2 v = unpack_h2(uu[k]);
              float sc = g1 + v.x;
              sc = fmaxf(sc, 0.01f * sc);
              float x = exp2f(sc * ee[k]);
              csum += x;
              acc += x * v.y;
            }
          }
        }
      }
    }
    if (curnode >= 0) atomicAdd(out + (size_t)curnode * FDIM + lane, acc);  // range-end: always atomic
    __syncthreads();   // lpay reuse safety for multi-chunk
  }
  part[t] = csum;
  __syncthreads();
  if (t < 64) {
    float tot = 0.0f;
    #pragma unroll
    for (int w = 0; w < 8; w++) tot += part[t + (w << 6)];
    atomicAdd(&colsum[t * 16], (double)tot);   // 128B line per feature
  }
}

// ---------- epilogue: out *= 1/colsum[feature], float4 ----------
__global__ __launch_bounds__(256) void scale_k(float4* __restrict__ out4,
                                               const double* __restrict__ colsum,
                                               int total4) {
  __shared__ float rinv_s[64];
  if (threadIdx.x < 64) rinv_s[threadIdx.x] = (float)(1.0 / colsum[threadIdx.x * 16]);
  __syncthreads();
  const float4* r4 = (const float4*)rinv_s;
  int idx = blockIdx.x * blockDim.x + threadIdx.x;
  int stride = gridDim.x * blockDim.x;
  for (int i = idx; i < total4; i += stride) {
    float4 v = out4[i];
    float4 r = r4[i & 15];
    v.x *= r.x; v.y *= r.y; v.z *= r.z; v.w *= r.w;
    out4[i] = v;
  }
}

extern "C" void kernel_launch(void* const* d_in, const int* in_sizes, int n_in,
                              void* d_out, int out_size, void* d_ws, size_t ws_size,
                              hipStream_t stream) {
  const float* h      = (const float*)d_in[0];
  const int*   adj    = (const int*)d_in[1];
  const float* amount = (const float*)d_in[2];
  const float* count  = (const float*)d_in[3];
  const float* fc_w   = (const float*)d_in[4];
  const float* fc_b   = (const float*)d_in[5];
  float* out = (float*)d_out;

  const int E = in_sizes[2];
  const int N = in_sizes[0] / FDIM;
  const int* src = adj;
  const int* dst = adj + E;
  const int nbkt  = (N + BMASK) >> BSHIFT;           // 128-node buckets (<=1024)
  const int nblkA = (E + CHUNKA - 1) / CHUNKA;
  const int nblkM = (E + CHUNKM - 1) / CHUNKM;
  const int npg   = (N + NB - 1) / NB;

  // ---- workspace layout (256B-aligned) ----
  char* ws = (char*)d_ws;
  size_t off = 0;
  auto alloc = [&](size_t bytes) { void* p = ws + off; off += (bytes + 255) & ~(size_t)255; return p; };
  float*    G1      = (float*)alloc((size_t)N * FDIM * sizeof(float));
  __half2*  P       = (__half2*)alloc((size_t)N * FDIM * sizeof(__half2));
  int2*     payload = (int2*)alloc((size_t)nbkt * CAPB * sizeof(int2));
  int*      cursor  = (int*)alloc(1024 * sizeof(int));
  float4*   mmpart  = (float4*)alloc((size_t)nblkM * sizeof(float4));
  double*   colsum  = (double*)alloc(1024 * sizeof(double));   // padded: [f*16]
  float*    mmf     = (float*)alloc(4 * sizeof(float));

  mp_k<<<nblkM + npg, 256, 0, stream>>>(amount, count, mmpart, h, fc_w, fc_b,
                                        G1, P, E, N, nblkM);
  init_k<<<1, 256, 0, stream>>>(mmpart, nblkM, mmf, cursor, nbkt, colsum);
  scatter_k<<<nblkA, 256, 0, stream>>>(src, dst, amount, count, mmf, cursor, payload, E, nbkt);
  fusedB_k<<<nbkt, 512, 0, stream>>>(payload, cursor, G1, (const unsigned*)P, colsum, out, E, nbkt);
  scale_k<<<1024, 256, 0, stream>>>((float4*)out, colsum, N * FDIM / 4);
}

// Round 14
// 276.172 us; speedup vs baseline: 1.0498x; 1.0133x over previous
//
#include <hip/hip_runtime.h>
#include <hip/hip_fp16.h>
#include <math.h>

#define FDIM   64
#define NB     64      // nodes per pre_gemm block
#define BSHIFT 6       // bucket = 64 nodes (block-exclusive in fusedB)
#define BMASK  63
#define NBKT_AL 1792   // max buckets (N <= 114688)
#define CHUNKA 3072    // edges per block in scatter (12/thread; LDS 44 KB -> 3 blk/CU)
#define CHUNKM 2048    // edges per block in mm sweep
#define CAP    1792    // LDS edge capacity per fusedB chunk (mean 1280, +14 sigma)
#define CAPB   2048    // fixed payload capacity per bucket (+21 sigma)

// ---------- mp_k: partitioned {minmax sweep | pre_gemm} (round-13, kept) ----------
__global__ __launch_bounds__(256) void mp_k(const float* __restrict__ amount,
                                            const float* __restrict__ count,
                                            float4* __restrict__ partial,
                                            const float* __restrict__ h,
                                            const float* __restrict__ fc_w,
                                            const float* __restrict__ fc_b,
                                            float* __restrict__ G1,
                                            __half2* __restrict__ P,
                                            int E, int N, int nblkM) {
  __shared__ float hs[NB * FDIM];   // 16 KB (mm branch uses first 64 B)
  const int t = threadIdx.x;
  if (blockIdx.x < nblkM) {
    float amin = 3.4e38f, amax = -3.4e38f, cmin = 3.4e38f, cmax = -3.4e38f;
    int e0 = blockIdx.x * CHUNKM + t * 8;
    if (e0 + 8 <= E) {
      #pragma unroll
      for (int q = 0; q < 8; q += 4) {
        float4 a4 = *(const float4*)(amount + e0 + q);
        float4 c4 = *(const float4*)(count + e0 + q);
        amin = fminf(amin, fminf(fminf(a4.x, a4.y), fminf(a4.z, a4.w)));
        amax = fmaxf(amax, fmaxf(fmaxf(a4.x, a4.y), fmaxf(a4.z, a4.w)));
        cmin = fminf(cmin, fminf(fminf(c4.x, c4.y), fminf(c4.z, c4.w)));
        cmax = fmaxf(cmax, fmaxf(fmaxf(c4.x, c4.y), fmaxf(c4.z, c4.w)));
      }
    } else {
      for (int e = e0; e < E; e++) {
        float a = amount[e], c = count[e];
        amin = fminf(amin, a); amax = fmaxf(amax, a);
        cmin = fminf(cmin, c); cmax = fmaxf(cmax, c);
      }
    }
    #pragma unroll
    for (int off = 32; off; off >>= 1) {
      amin = fminf(amin, __shfl_down(amin, off));
      amax = fmaxf(amax, __shfl_down(amax, off));
      cmin = fminf(cmin, __shfl_down(cmin, off));
      cmax = fmaxf(cmax, __shfl_down(cmax, off));
    }
    float4* lred = (float4*)hs;
    if ((t & 63) == 0) lred[t >> 6] = make_float4(amin, amax, cmin, cmax);
    __syncthreads();
    if (t == 0) {
      float4 r = lred[0];
      #pragma unroll
      for (int w = 1; w < 4; w++) {
        r.x = fminf(r.x, lred[w].x); r.y = fmaxf(r.y, lred[w].y);
        r.z = fminf(r.z, lred[w].z); r.w = fmaxf(r.w, lred[w].w);
      }
      partial[blockIdx.x] = r;
    }
  } else {
    const int pgb = blockIdx.x - nblkM;
    const int o = t & 63;
    const int grp = t >> 6;
    const int half = grp & 1;
    const int rh = grp >> 1;
    float w[FDIM];
    const float* wrow = fc_w + o * 128 + half * 64;
    #pragma unroll
    for (int f = 0; f < FDIM; f += 4) {
      float4 v = *(const float4*)(wrow + f);
      w[f] = v.x; w[f + 1] = v.y; w[f + 2] = v.z; w[f + 3] = v.w;
    }
    const float bias = (half == 0) ? fc_b[o] : 0.0f;
    const int n0 = pgb * NB;
    const int nrows = min(NB, N - n0);
    for (int i = t; i < nrows * FDIM; i += 256) hs[i] = h[(size_t)n0 * FDIM + i];
    __syncthreads();
    const int r0 = rh * (NB / 2);
    const int r1 = min(r0 + NB / 2, nrows);
    for (int n = r0; n < r1; n++) {
      float4 a4 = make_float4(0.f, 0.f, 0.f, 0.f);
      #pragma unroll
      for (int f = 0; f < FDIM; f += 4) {
        float4 hv = *(const float4*)(&hs[n * FDIM + f]);
        a4.x += hv.x * w[f];
        a4.y += hv.y * w[f + 1];
        a4.z += hv.z * w[f + 2];
        a4.w += hv.w * w[f + 3];
      }
      float acc = (a4.x + a4.y) + (a4.z + a4.w) + bias;
      if (half == 0) {
        G1[(size_t)(n0 + n) * FDIM + o] = acc;
      } else {
        P[(size_t)(n0 + n) * FDIM + o] =
            __halves2half2(__float2half(acc), __float2half(hs[n * FDIM + o]));
      }
    }
  }
}

// ---------- init_k: minmax final reduce + cursor init + colsum zero ----------
__global__ __launch_bounds__(256) void init_k(const float4* __restrict__ partial,
                                              int nb, float* __restrict__ mmf,
                                              int* __restrict__ cursor, int nbkt,
                                              double* __restrict__ colsum) {
  int t = threadIdx.x;
  for (int k = t; k < nbkt; k += 256) cursor[k] = k * CAPB;
  for (int i = t; i < 1024; i += 256) colsum[i] = 0.0;
  float amin = 3.4e38f, amax = -3.4e38f, cmin = 3.4e38f, cmax = -3.4e38f;
  for (int i = t; i < nb; i += 256) {
    float4 p = partial[i];
    amin = fminf(amin, p.x); amax = fmaxf(amax, p.y);
    cmin = fminf(cmin, p.z); cmax = fmaxf(cmax, p.w);
  }
  #pragma unroll
  for (int off = 32; off; off >>= 1) {
    amin = fminf(amin, __shfl_down(amin, off));
    amax = fmaxf(amax, __shfl_down(amax, off));
    cmin = fminf(cmin, __shfl_down(cmin, off));
    cmax = fmaxf(cmax, __shfl_down(cmax, off));
  }
  __shared__ float4 lred[4];
  if ((t & 63) == 0) lred[t >> 6] = make_float4(amin, amax, cmin, cmax);
  __syncthreads();
  if (t == 0) {
    float4 r = lred[0];
    #pragma unroll
    for (int w = 1; w < 4; w++) {
      r.x = fminf(r.x, lred[w].x); r.y = fmaxf(r.y, lred[w].y);
      r.z = fminf(r.z, lred[w].z); r.w = fmaxf(r.w, lred[w].w);
    }
    mmf[0] = r.x; mmf[1] = r.y; mmf[2] = r.z; mmf[3] = r.w;
  }
}

// ---------- scatter: LDS counting sort -> fixed-capacity bucket regions ----------
// 64-node buckets (nbkt<=1792). Two LDS tables (delta-array trick: baseb is
// reused to hold sbase-baseb after reservation) keep LDS at ~44 KB -> 3 blk/CU.
// payload.x = (dst << 8) | fine(6b), payload.y = (ew * log2e) bits
__global__ __launch_bounds__(256) void scatter_k(const int* __restrict__ src,
                                                 const int* __restrict__ dst,
                                                 const float* __restrict__ amount,
                                                 const float* __restrict__ count,
                                                 const float* __restrict__ mmf,
                                                 int* __restrict__ cursor,
                                                 int2* __restrict__ payload,
                                                 int E, int nbkt) {
  __shared__ int cntb[NBKT_AL];
  __shared__ int baseb[NBKT_AL];      // local base, then delta (sbase-baseb)
  __shared__ int wsum[4];
  __shared__ int2 lpay[CHUNKA];
  __shared__ unsigned short lbkt[CHUNKA];
  const int t = threadIdx.x, blk = blockIdx.x;
  for (int k = t; k < nbkt; k += 256) cntb[k] = 0;
  __syncthreads();
  const float amin = mmf[0], amax = mmf[1], cmin = mmf[2], cmax = mmf[3];
  const float L2E = 1.4426950408889634f;
  const float ascale = 0.5f * L2E / (amax - amin + 1e-8f);
  const float cscale = 0.5f * L2E / (cmax - cmin + 1e-8f);
  int e0 = blk * CHUNKA + t * 12;
  const bool full = (e0 + 12 <= E);
  int4 S[3]; int4 D[3]; float4 A[3]; float4 C[3];
  if (full) {
    #pragma unroll
    for (int q = 0; q < 3; q++) {
      S[q] = *(const int4*)(src + e0 + 4 * q);
      D[q] = *(const int4*)(dst + e0 + 4 * q);
      A[q] = *(const float4*)(amount + e0 + 4 * q);
      C[q] = *(const float4*)(count + e0 + 4 * q);
      atomicAdd(&cntb[S[q].x >> BSHIFT], 1);
      atomicAdd(&cntb[S[q].y >> BSHIFT], 1);
      atomicAdd(&cntb[S[q].z >> BSHIFT], 1);
      atomicAdd(&cntb[S[q].w >> BSHIFT], 1);
    }
  } else {
    for (int e = e0; e < E; e++) atomicAdd(&cntb[src[e] >> BSHIFT], 1);
  }
  __syncthreads();
  // exclusive scan of cntb[0..nbkt) -> baseb : each wave owns 448 buckets
  {
    const int wv = t >> 6, ln = t & 63;
    int carry = 0;
    #pragma unroll
    for (int c = 0; c < 7; c++) {
      int idx = wv * 448 + (c << 6) + ln;
      int x = (idx < nbkt) ? cntb[idx] : 0;
      int v = x;
      #pragma unroll
      for (int off = 1; off < 64; off <<= 1) {
        int u = __shfl_up(v, off);
        if (ln >= off) v += u;
      }
      if (idx < nbkt) baseb[idx] = carry + v - x;
      carry += __shfl(v, 63);
    }
    if (ln == 0) wsum[wv] = carry;
  }
  __syncthreads();
  {
    const int wv = t >> 6, ln = t & 63;
    int wpre = 0;
    #pragma unroll
    for (int i = 0; i < 4; i++) wpre += (i < wv) ? wsum[i] : 0;
    if (wpre) {
      #pragma unroll
      for (int c = 0; c < 7; c++) {
        int idx = wv * 448 + (c << 6) + ln;
        if (idx < nbkt) baseb[idx] += wpre;
      }
    }
  }
  __syncthreads();
  // reserve global space per nonzero bucket; cntb <- local base; baseb <- delta
  for (int k = t; k < nbkt; k += 256) {
    int cnt = cntb[k];
    int bb = baseb[k];
    cntb[k] = bb;
    if (cnt) {
      int sb = atomicAdd(&cursor[k], cnt);
      baseb[k] = sb - bb;           // delta: global pos = delta + local pos
    }
  }
  __syncthreads();
  auto ins = [&](int s, int d, float a, float c) {
    int b = s >> BSHIFT;
    float ew = (a - amin) * ascale + (c - cmin) * cscale;
    int pos = atomicAdd(&cntb[b], 1);
    lpay[pos] = make_int2((d << 8) | (s & BMASK), __float_as_int(ew));
    lbkt[pos] = (unsigned short)b;
  };
  if (full) {
    #pragma unroll
    for (int q = 0; q < 3; q++) {
      ins(S[q].x, D[q].x, A[q].x, C[q].x);
      ins(S[q].y, D[q].y, A[q].y, C[q].y);
      ins(S[q].z, D[q].z, A[q].z, C[q].z);
      ins(S[q].w, D[q].w, A[q].w, C[q].w);
    }
  } else {
    for (int e = e0; e < E; e++) ins(src[e], dst[e], amount[e], count[e]);
  }
  __syncthreads();
  const int ned = min(CHUNKA, E - blk * CHUNKA);
  for (int i = t; i < ned; i += 256) {
    int bk = lbkt[i];
    int gpos = baseb[bk] + i;
    if (gpos < (bk + 1) * CAPB)          // overflow guard (statistically unreachable)
      payload[gpos] = lpay[i];
  }
}

__device__ __forceinline__ float2 unpack_h2(unsigned u) {
  __half2 v = *(__half2*)&u;
  return make_float2(__low2float(v), __high2float(v));
}

// ---------- fusedB: one 8-wave block per 64-node bucket; LDS fine-sort +
// register accumulate. 1563 blocks x 8 waves = 48.9 waves/CU queued (1.5x
// oversubscribed); LDS ~17 KB so the 4-block wave limit binds -> full 32-wave
// residency. Exclusive ownership -> plain stores, atomicAdd at boundaries.
__global__ __launch_bounds__(512) void fusedB_k(const int2* __restrict__ payload,
                                                const int* __restrict__ cursor,
                                                const float* __restrict__ G1,
                                                const unsigned* __restrict__ P,
                                                double* __restrict__ colsum,
                                                float* __restrict__ out,
                                                int E, int nbkt) {
  __shared__ int2 lpay[CAP];        // 14 KB
  __shared__ int fcnt[64];
  __shared__ int fcur[64];
  __shared__ float part[512];
  const int b = blockIdx.x;
  const int t = threadIdx.x;
  const int lane = t & 63;
  const int wv = __builtin_amdgcn_readfirstlane(t >> 6);   // 0..7
  const int node0 = b << BSHIFT;
  const int base = b * CAPB;
  int end = cursor[b];
  if (end > base + CAPB) end = base + CAPB;
  const int nchunks = (end - base + CAP - 1) / CAP;        // ==1 in practice
  const bool multi = (nchunks > 1);                        // safety fallback
  float csum = 0.0f;
  for (int c = 0; c < nchunks; c++) {
    const int cs = base + c * CAP;
    const int m = min(CAP, end - cs);
    if (t < 64) fcnt[t] = 0;
    __syncthreads();
    // stage to regs (static-indexed) + fine histogram
    int2 myp0, myp1, myp2, myp3;
    {
      int i;
      i = t;        if (i < m) { myp0 = payload[cs + i]; atomicAdd(&fcnt[myp0.x & 63], 1); }
      i = t + 512;  if (i < m) { myp1 = payload[cs + i]; atomicAdd(&fcnt[myp1.x & 63], 1); }
      i = t + 1024; if (i < m) { myp2 = payload[cs + i]; atomicAdd(&fcnt[myp2.x & 63], 1); }
      i = t + 1536; if (i < m) { myp3 = payload[cs + i]; atomicAdd(&fcnt[myp3.x & 63], 1); }
    }
    __syncthreads();
    // wave 0: exclusive scan of fcnt[0..64) -> fcur (single 64-lane scan)
    if (wv == 0) {
      int x = fcnt[lane];
      int v = x;
      #pragma unroll
      for (int off = 1; off < 64; off <<= 1) {
        int u = __shfl_up(v, off);
        if (lane >= off) v += u;
      }
      fcur[lane] = v - x;
    }
    __syncthreads();
    // scatter regs -> lpay (fine-sorted)
    {
      int i;
      i = t;        if (i < m) lpay[atomicAdd(&fcur[myp0.x & 63], 1)] = myp0;
      i = t + 512;  if (i < m) lpay[atomicAdd(&fcur[myp1.x & 63], 1)] = myp1;
      i = t + 1024; if (i < m) lpay[atomicAdd(&fcur[myp2.x & 63], 1)] = myp2;
      i = t + 1536; if (i < m) lpay[atomicAdd(&fcur[myp3.x & 63], 1)] = myp3;
    }
    __syncthreads();
    // per-wave subranges over the sorted segment
    const int per = (((m + 7) >> 3) + 63) & ~63;
    const int ws = wv * per;
    const int we = min(ws + per, m);
    int curnode = -1;
    bool firstf = true;
    float acc = 0.0f, g1 = 0.0f;
    auto flush_to = [&](int node) {   // wave-uniform control
      if (curnode >= 0) {
        float* dp = out + (size_t)curnode * FDIM + lane;
        if (multi || firstf) { atomicAdd(dp, acc); firstf = false; }
        else *dp = acc;
      }
      curnode = node; acc = 0.0f;
      g1 = G1[(size_t)node * FDIM + lane];
    };
    for (int c0 = ws; c0 < we; c0 += 64) {
      const int mm = min(64, we - c0);
      int2 p = make_int2(0, 0);
      if (lane < mm) p = lpay[c0 + lane];
      if (mm == 64) {
        #pragma unroll 1
        for (int j = 0; j < 64; j += 16) {
          int xs[16]; float ee[16]; unsigned uu[16];
          #pragma unroll
          for (int k = 0; k < 16; k++) {
            xs[k] = __builtin_amdgcn_readlane(p.x, j + k);
            ee[k] = __int_as_float(__builtin_amdgcn_readlane(p.y, j + k));
          }
          #pragma unroll
          for (int k = 0; k < 16; k++) {
            unsigned off = (((unsigned)xs[k]) & 0xFFFFFF00u) | ((unsigned)lane << 2);
            uu[k] = *(const unsigned*)((const char*)P + off);
          }
          #pragma unroll
          for (int k = 0; k < 16; k++) {
            int node = node0 + (xs[k] & 63);
            if (node != curnode) flush_to(node);
            float2 v = unpack_h2(uu[k]);
            float sc = g1 + v.x;
            sc = fmaxf(sc, 0.01f * sc);        // leaky_relu
            float x = exp2f(sc * ee[k]);       // log2e folded into ew
            csum += x;
            acc += x * v.y;
          }
        }
      } else {
        for (int j = 0; j < mm; j += 16) {
          const int rem = mm - j;
          int xs[16]; float ee[16]; unsigned uu[16];
          #pragma unroll
          for (int k = 0; k < 16; k++) {
            xs[k] = __builtin_amdgcn_readlane(p.x, j + k);
            ee[k] = __int_as_float(__builtin_amdgcn_readlane(p.y, j + k));
          }
          #pragma unroll
          for (int k = 0; k < 16; k++) {
            unsigned off = (((unsigned)xs[k]) & 0xFFFFFF00u) | ((unsigned)lane << 2);
            uu[k] = *(const unsigned*)((const char*)P + off);
          }
          #pragma unroll
          for (int k = 0; k < 16; k++) {
            if (k < rem) {                      // wave-uniform guard
              int node = node0 + (xs[k] & 63);
              if (node != curnode) flush_to(node);
              float2 v = unpack_h2(uu[k]);
              float sc = g1 + v.x;
              sc = fmaxf(sc, 0.01f * sc);
              float x = exp2f(sc * ee[k]);
              csum += x;
              acc += x * v.y;
            }
          }
        }
      }
    }
    if (curnode >= 0) atomicAdd(out + (size_t)curnode * FDIM + lane, acc);  // range-end: always atomic
    __syncthreads();   // lpay reuse safety for multi-chunk
  }
  part[t] = csum;
  __syncthreads();
  if (t < 64) {
    float tot = 0.0f;
    #pragma unroll
    for (int w = 0; w < 8; w++) tot += part[t + (w << 6)];
    atomicAdd(&colsum[t * 16], (double)tot);   // 128B line per feature
  }
}

// ---------- epilogue: out *= 1/colsum[feature], float4 ----------
__global__ __launch_bounds__(256) void scale_k(float4* __restrict__ out4,
                                               const double* __restrict__ colsum,
                                               int total4) {
  __shared__ float rinv_s[64];
  if (threadIdx.x < 64) rinv_s[threadIdx.x] = (float)(1.0 / colsum[threadIdx.x * 16]);
  __syncthreads();
  const float4* r4 = (const float4*)rinv_s;
  int idx = blockIdx.x * blockDim.x + threadIdx.x;
  int stride = gridDim.x * blockDim.x;
  for (int i = idx; i < total4; i += stride) {
    float4 v = out4[i];
    float4 r = r4[i & 15];
    v.x *= r.x; v.y *= r.y; v.z *= r.z; v.w *= r.w;
    out4[i] = v;
  }
}

extern "C" void kernel_launch(void* const* d_in, const int* in_sizes, int n_in,
                              void* d_out, int out_size, void* d_ws, size_t ws_size,
                              hipStream_t stream) {
  const float* h      = (const float*)d_in[0];
  const int*   adj    = (const int*)d_in[1];
  const float* amount = (const float*)d_in[2];
  const float* count  = (const float*)d_in[3];
  const float* fc_w   = (const float*)d_in[4];
  const float* fc_b   = (const float*)d_in[5];
  float* out = (float*)d_out;

  const int E = in_sizes[2];
  const int N = in_sizes[0] / FDIM;
  const int* src = adj;
  const int* dst = adj + E;
  const int nbkt  = (N + BMASK) >> BSHIFT;           // 64-node buckets (<=1792)
  const int nblkA = (E + CHUNKA - 1) / CHUNKA;
  const int nblkM = (E + CHUNKM - 1) / CHUNKM;
  const int npg   = (N + NB - 1) / NB;

  // ---- workspace layout (256B-aligned) ----
  char* ws = (char*)d_ws;
  size_t off = 0;
  auto alloc = [&](size_t bytes) { void* p = ws + off; off += (bytes + 255) & ~(size_t)255; return p; };
  float*    G1      = (float*)alloc((size_t)N * FDIM * sizeof(float));
  __half2*  P       = (__half2*)alloc((size_t)N * FDIM * sizeof(__half2));
  int2*     payload = (int2*)alloc((size_t)nbkt * CAPB * sizeof(int2));
  int*      cursor  = (int*)alloc((size_t)NBKT_AL * sizeof(int));
  float4*   mmpart  = (float4*)alloc((size_t)nblkM * sizeof(float4));
  double*   colsum  = (double*)alloc(1024 * sizeof(double));   // padded: [f*16]
  float*    mmf     = (float*)alloc(4 * sizeof(float));

  mp_k<<<nblkM + npg, 256, 0, stream>>>(amount, count, mmpart, h, fc_w, fc_b,
                                        G1, P, E, N, nblkM);
  init_k<<<1, 256, 0, stream>>>(mmpart, nblkM, mmf, cursor, nbkt, colsum);
  scatter_k<<<nblkA, 256, 0, stream>>>(src, dst, amount, count, mmf, cursor, payload, E, nbkt);
  fusedB_k<<<nbkt, 512, 0, stream>>>(payload, cursor, G1, (const unsigned*)P, colsum, out, E, nbkt);
  scale_k<<<1024, 256, 0, stream>>>((float4*)out, colsum, N * FDIM / 4);
}